// Round 1
// baseline (1054.476 us; speedup 1.0000x reference)
//
#include <hip/hip_runtime.h>
#include <math.h>

// Problem dims (fixed by setup_inputs)
constexpr int B_ = 2, T_ = 512, D_ = 256, H_ = 4, DK_ = 64;
constexpr int BT_ = B_ * T_;    // 1024 rows
constexpr int D4_ = 4 * D_;     // 1024 ffn dim

// constant-index float4 element extract (only use under full unroll)
#define F4E(v,i) ((i)==0?(v).x:((i)==1?(v).y:((i)==2?(v).z:(v).w)))

// ---------------- LayerNorm: one block (256 thr) per row ----------------
__global__ __launch_bounds__(256) void k_ln(const float* __restrict__ in,
                                            const float* __restrict__ g,
                                            const float* __restrict__ be,
                                            float* __restrict__ out) {
  int row = blockIdx.x, t = threadIdx.x, lane = t & 63, wid = t >> 6;
  __shared__ float red[4];
  float v = in[row * D_ + t];
  float s = v;
  #pragma unroll
  for (int o = 32; o > 0; o >>= 1) s += __shfl_xor(s, o, 64);
  if (lane == 0) red[wid] = s;
  __syncthreads();
  float mean = (red[0] + red[1] + red[2] + red[3]) * (1.0f / D_);
  float d = v - mean;
  float s2 = d * d;
  #pragma unroll
  for (int o = 32; o > 0; o >>= 1) s2 += __shfl_xor(s2, o, 64);
  __syncthreads();  // everyone has read red[] as mean
  if (lane == 0) red[wid] = s2;
  __syncthreads();
  float var = (red[0] + red[1] + red[2] + red[3]) * (1.0f / D_);
  out[row * D_ + t] = d / sqrtf(var + 1e-5f) * g[t] + be[t];
}

// ---------------- QKV projection: 8 rows/block, 128 blocks ----------------
// writes q,k,v in (B,H,T,DK) layout
__global__ __launch_bounds__(256) void k_qkv(const float* __restrict__ h,
    const float* __restrict__ Wq, const float* __restrict__ bq,
    const float* __restrict__ Wk, const float* __restrict__ bk,
    const float* __restrict__ Wv, const float* __restrict__ bv,
    float* __restrict__ q, float* __restrict__ k, float* __restrict__ v) {
  __shared__ float hs[8][D_];
  int t = threadIdx.x, row0 = blockIdx.x * 8;
  #pragma unroll
  for (int r = 0; r < 8; r++) hs[r][t] = h[(row0 + r) * D_ + t];
  __syncthreads();
  float qa[8], ka[8], va[8];
  float bqc = bq[t], bkc = bk[t], bvc = bv[t];
  #pragma unroll
  for (int r = 0; r < 8; r++) { qa[r] = bqc; ka[r] = bkc; va[r] = bvc; }
  for (int d = 0; d < D_; d += 4) {
    float4 hv[8];
    #pragma unroll
    for (int r = 0; r < 8; r++) hv[r] = *(const float4*)&hs[r][d];
    #pragma unroll
    for (int i = 0; i < 4; i++) {
      float wq = Wq[(d + i) * D_ + t], wk = Wk[(d + i) * D_ + t], wv = Wv[(d + i) * D_ + t];
      #pragma unroll
      for (int r = 0; r < 8; r++) {
        float hvv = F4E(hv[r], i);
        qa[r] = fmaf(hvv, wq, qa[r]);
        ka[r] = fmaf(hvv, wk, ka[r]);
        va[r] = fmaf(hvv, wv, va[r]);
      }
    }
  }
  int b = row0 / T_, hh = t >> 6, dd = t & 63;
  #pragma unroll
  for (int r = 0; r < 8; r++) {
    int tt = row0 + r - b * T_;
    size_t idx = ((size_t)(b * H_ + hh) * T_ + tt) * DK_ + dd;
    q[idx] = qa[r]; k[idx] = ka[r]; v[idx] = va[r];
  }
}

// ---------------- w = Wr-folded query, cq = br-folded const ----------------
// w[(b*T+i)*H + h][c] = sum_dd Wr[c, h*64+dd] * (q+r_bias)[b,h,i,dd]
__global__ __launch_bounds__(256) void k_wbias(const float* __restrict__ q,
    const float* __restrict__ rbias, const float* __restrict__ Wr,
    const float* __restrict__ br, float* __restrict__ w, float* __restrict__ cq) {
  __shared__ float us[8][D_];
  int t = threadIdx.x, row0 = blockIdx.x * 8, b = row0 / T_;
  int hh = t >> 6, dd = t & 63;
  float rb = rbias[t];
  #pragma unroll
  for (int r = 0; r < 8; r++) {
    int tt = row0 + r - b * T_;
    us[r][t] = q[((size_t)(b * H_ + hh) * T_ + tt) * DK_ + dd] + rb;
  }
  __syncthreads();
  float acc[8][4];
  #pragma unroll
  for (int r = 0; r < 8; r++)
    #pragma unroll
    for (int h = 0; h < 4; h++) acc[r][h] = 0.0f;
  for (int h = 0; h < 4; h++) {
    for (int d4 = 0; d4 < 64; d4 += 4) {
      int cc = h * 64 + d4;
      float4 wr4 = *(const float4*)&Wr[(size_t)t * D_ + cc];
      #pragma unroll
      for (int r = 0; r < 8; r++) {
        float4 u4 = *(const float4*)&us[r][cc];
        acc[r][h] = fmaf(wr4.x, u4.x, fmaf(wr4.y, u4.y,
                    fmaf(wr4.z, u4.z, fmaf(wr4.w, u4.w, acc[r][h]))));
      }
    }
  }
  #pragma unroll
  for (int r = 0; r < 8; r++) {
    int bt = row0 + r;
    #pragma unroll
    for (int h = 0; h < 4; h++) w[(size_t)(bt * 4 + h) * D_ + t] = acc[r][h];
  }
  if (t < 32) {
    int r = t >> 2, h = t & 3;
    float s = 0;
    for (int d2 = 0; d2 < 64; d2++) s += us[r][h * 64 + d2] * br[h * 64 + d2];
    cq[(row0 + r) * 4 + h] = s;
  }
}

// ---------------- fused scores + softmax + PV: 1 block per (b,i) ----------------
__global__ __launch_bounds__(256) void k_attn(const float* __restrict__ r,
    const int* __restrict__ mask, const float* __restrict__ q,
    const float* __restrict__ k, const float* __restrict__ v,
    const float* __restrict__ w, const float* __restrict__ cq,
    float* __restrict__ attn) {
  __shared__ float sw[H_ * D_];   // 4 KB
  __shared__ float sq[D_];        // 1 KB
  __shared__ float sc[H_][T_];    // 8 KB: scores then unnormalized p
  __shared__ float scq[H_];
  __shared__ float sinv[H_];
  int t = threadIdx.x, bi = blockIdx.x;
  int b = bi >> 9, i = bi & (T_ - 1);
  #pragma unroll
  for (int u = 0; u < 4; u++) sw[u * 256 + t] = w[(size_t)bi * 1024 + u * 256 + t];
  sq[t] = q[((size_t)(b * H_ + (t >> 6)) * T_ + i) * DK_ + (t & 63)];
  if (t < 4) scq[t] = cq[bi * 4 + t];
  __syncthreads();

  float acc0[H_], acc1[H_];
  #pragma unroll
  for (int h = 0; h < H_; h++) { acc0[h] = 0; acc1[h] = 0; }

  // QK^T part: thread t owns rows j=t and j=t+256
  #pragma unroll
  for (int jj = 0; jj < 2; jj++) {
    int j = t + jj * 256;
    #pragma unroll
    for (int h = 0; h < H_; h++) {
      const float4* kp = (const float4*)&k[((size_t)(b * H_ + h) * T_ + j) * DK_];
      const float4* qp = (const float4*)&sq[h * DK_];
      float s = 0;
      #pragma unroll
      for (int d4 = 0; d4 < 16; d4++) {
        float4 kv = kp[d4], qv = qp[d4];
        s = fmaf(kv.x, qv.x, s); s = fmaf(kv.y, qv.y, s);
        s = fmaf(kv.z, qv.z, s); s = fmaf(kv.w, qv.w, s);
      }
      if (jj == 0) acc0[h] = s; else acc1[h] = s;
    }
  }
  // r·w part — streams 512 KB of r per block, read exactly once globally
  {
    const float4* rp0 = (const float4*)(r + ((size_t)(b * T_ + i) * T_ + t) * D_);
    const float4* rp1 = rp0 + (256 * D_) / 4;
    #pragma unroll 4
    for (int d4 = 0; d4 < 64; d4++) {
      float4 r0 = rp0[d4], r1 = rp1[d4];
      #pragma unroll
      for (int h = 0; h < H_; h++) {
        float4 wv = *(const float4*)&sw[h * D_ + 4 * d4];
        acc0[h] = fmaf(r0.x, wv.x, fmaf(r0.y, wv.y, fmaf(r0.z, wv.z, fmaf(r0.w, wv.w, acc0[h]))));
        acc1[h] = fmaf(r1.x, wv.x, fmaf(r1.y, wv.y, fmaf(r1.z, wv.z, fmaf(r1.w, wv.w, acc1[h]))));
      }
    }
  }
  const float scale = 0.125f;  // 1/sqrt(64)
  int mbase = (b * T_ + i) * T_;
  #pragma unroll
  for (int jj = 0; jj < 2; jj++) {
    int j = t + jj * 256;
    int mv = mask[mbase + j];
    #pragma unroll
    for (int h = 0; h < H_; h++) {
      float s = ((jj == 0 ? acc0[h] : acc1[h]) + scq[h]) * scale;
      if (mv == 0) s = -1e9f;
      sc[h][j] = s;
    }
  }
  __syncthreads();
  // softmax: wave wid handles head wid (H_ == 4 waves)
  {
    int h = t >> 6, lane = t & 63;
    float vals[8];
    float m = -3.0e38f;
    #pragma unroll
    for (int kk = 0; kk < 8; kk++) { vals[kk] = sc[h][lane + 64 * kk]; m = fmaxf(m, vals[kk]); }
    #pragma unroll
    for (int o = 32; o > 0; o >>= 1) m = fmaxf(m, __shfl_xor(m, o, 64));
    float ss = 0;
    #pragma unroll
    for (int kk = 0; kk < 8; kk++) {
      float e = expf(vals[kk] - m);
      sc[h][lane + 64 * kk] = e;
      ss += e;
    }
    #pragma unroll
    for (int o = 32; o > 0; o >>= 1) ss += __shfl_xor(ss, o, 64);
    if (lane == 0) sinv[h] = 1.0f / ss;
  }
  __syncthreads();
  // PV: thread t -> (head h, dim d); v reads coalesced, p broadcast from LDS
  {
    int h = t >> 6, d = t & 63;
    const float* vp = &v[(size_t)(b * H_ + h) * T_ * DK_ + d];
    float a2 = 0;
    #pragma unroll 4
    for (int j = 0; j < T_; j += 4) {
      float4 p4 = *(const float4*)&sc[h][j];
      a2 = fmaf(p4.x, vp[(size_t)j * 64], a2);
      a2 = fmaf(p4.y, vp[(size_t)(j + 1) * 64], a2);
      a2 = fmaf(p4.z, vp[(size_t)(j + 2) * 64], a2);
      a2 = fmaf(p4.w, vp[(size_t)(j + 3) * 64], a2);
    }
    attn[(size_t)bi * D_ + t] = a2 * sinv[h];
  }
}

// ---------------- O-proj + residual: x1 = x + attn@Wo + bo ----------------
__global__ __launch_bounds__(256) void k_proj(const float* __restrict__ a,
    const float* __restrict__ Wo, const float* __restrict__ bo,
    const float* __restrict__ x, float* __restrict__ x1) {
  __shared__ float as[8][D_];
  int t = threadIdx.x, row0 = blockIdx.x * 8;
  #pragma unroll
  for (int r = 0; r < 8; r++) as[r][t] = a[(row0 + r) * D_ + t];
  __syncthreads();
  float acc[8];
  float bc = bo[t];
  #pragma unroll
  for (int r = 0; r < 8; r++) acc[r] = bc;
  for (int d = 0; d < D_; d += 4) {
    float4 av[8];
    #pragma unroll
    for (int r = 0; r < 8; r++) av[r] = *(const float4*)&as[r][d];
    #pragma unroll
    for (int i = 0; i < 4; i++) {
      float ww = Wo[(d + i) * D_ + t];
      #pragma unroll
      for (int r = 0; r < 8; r++) acc[r] = fmaf(F4E(av[r], i), ww, acc[r]);
    }
  }
  #pragma unroll
  for (int r = 0; r < 8; r++)
    x1[(row0 + r) * D_ + t] = x[(row0 + r) * D_ + t] + acc[r];
}

// ---------------- FFN1: mid = gelu_exact(h2@W1 + fb1) ----------------
__global__ __launch_bounds__(256) void k_ffn1(const float* __restrict__ h2,
    const float* __restrict__ W1, const float* __restrict__ fb1,
    float* __restrict__ mid) {
  __shared__ float hs[8][D_];
  int t = threadIdx.x, row0 = blockIdx.x * 8;
  #pragma unroll
  for (int r = 0; r < 8; r++) hs[r][t] = h2[(row0 + r) * D_ + t];
  __syncthreads();
  float acc[8][4];
  #pragma unroll
  for (int c = 0; c < 4; c++) {
    float bb = fb1[t + c * 256];
    #pragma unroll
    for (int r = 0; r < 8; r++) acc[r][c] = bb;
  }
  for (int d = 0; d < D_; d += 4) {
    float4 hv[8];
    #pragma unroll
    for (int r = 0; r < 8; r++) hv[r] = *(const float4*)&hs[r][d];
    #pragma unroll
    for (int i = 0; i < 4; i++) {
      float wv[4];
      #pragma unroll
      for (int c = 0; c < 4; c++) wv[c] = W1[(size_t)(d + i) * D4_ + t + c * 256];
      #pragma unroll
      for (int r = 0; r < 8; r++) {
        float hvv = F4E(hv[r], i);
        #pragma unroll
        for (int c = 0; c < 4; c++) acc[r][c] = fmaf(hvv, wv[c], acc[r][c]);
      }
    }
  }
  #pragma unroll
  for (int r = 0; r < 8; r++)
    #pragma unroll
    for (int c = 0; c < 4; c++) {
      float val = acc[r][c];
      float ge = 0.5f * val * (1.0f + erff(val * 0.70710678118654752f));
      mid[(size_t)(row0 + r) * D4_ + t + c * 256] = ge;
    }
}

// ---------------- FFN2 + residual: out = x1 + mid@W2 + fb2 ----------------
__global__ __launch_bounds__(256) void k_ffn2(const float* __restrict__ mid,
    const float* __restrict__ W2, const float* __restrict__ fb2,
    const float* __restrict__ x1, float* __restrict__ out) {
  __shared__ float ms[8][D4_];  // 32 KB
  int t = threadIdx.x, row0 = blockIdx.x * 8;
  #pragma unroll
  for (int r = 0; r < 8; r++)
    #pragma unroll
    for (int c = 0; c < 4; c++)
      ms[r][t + c * 256] = mid[(size_t)(row0 + r) * D4_ + t + c * 256];
  __syncthreads();
  float acc[8];
  float bb = fb2[t];
  #pragma unroll
  for (int r = 0; r < 8; r++) acc[r] = bb;
  for (int d = 0; d < D4_; d += 4) {
    float4 mv[8];
    #pragma unroll
    for (int r = 0; r < 8; r++) mv[r] = *(const float4*)&ms[r][d];
    #pragma unroll
    for (int i = 0; i < 4; i++) {
      float ww = W2[(size_t)(d + i) * D_ + t];
      #pragma unroll
      for (int r = 0; r < 8; r++) acc[r] = fmaf(F4E(mv[r], i), ww, acc[r]);
    }
  }
  #pragma unroll
  for (int r = 0; r < 8; r++)
    out[(row0 + r) * D_ + t] = x1[(row0 + r) * D_ + t] + acc[r];
}

extern "C" void kernel_launch(void* const* d_in, const int* in_sizes, int n_in,
                              void* d_out, int out_size, void* d_ws, size_t ws_size,
                              hipStream_t stream) {
  const float* x     = (const float*)d_in[0];
  const float* r     = (const float*)d_in[1];
  const int*   mask  = (const int*)d_in[2];
  // d_in[3]=layer, d_in[4]=info (unused)
  const float* Wq = (const float*)d_in[5];  const float* bq = (const float*)d_in[6];
  const float* Wk = (const float*)d_in[7];  const float* bk = (const float*)d_in[8];
  const float* Wv = (const float*)d_in[9];  const float* bv = (const float*)d_in[10];
  const float* Wr = (const float*)d_in[11]; const float* br = (const float*)d_in[12];
  const float* rbias = (const float*)d_in[13];
  const float* Wo = (const float*)d_in[14]; const float* bo = (const float*)d_in[15];
  const float* g1 = (const float*)d_in[16]; const float* b1 = (const float*)d_in[17];
  const float* g2 = (const float*)d_in[18]; const float* b2 = (const float*)d_in[19];
  const float* W1 = (const float*)d_in[20]; const float* fb1 = (const float*)d_in[21];
  const float* W2 = (const float*)d_in[22]; const float* fb2 = (const float*)d_in[23];
  float* out = (float*)d_out;

  float* ws = (float*)d_ws;
  float* h1b   = ws;                 // 262144
  float* qb    = ws + 262144;        // 262144
  float* kb    = ws + 524288;        // 262144
  float* vb    = ws + 786432;        // 262144
  float* wb    = ws + 1048576;       // 1048576
  float* cqb   = ws + 2097152;       // 4096
  float* attnb = ws + 2101248;       // 262144
  float* x1b   = ws + 2363392;       // 262144
  float* h2b   = ws + 2625536;       // 262144
  float* midb  = ws + 2887680;       // 1048576  (total ~15.7 MB)

  k_ln  <<<BT_,     256, 0, stream>>>(x, g1, b1, h1b);
  k_qkv <<<BT_ / 8, 256, 0, stream>>>(h1b, Wq, bq, Wk, bk, Wv, bv, qb, kb, vb);
  k_wbias<<<BT_ / 8,256, 0, stream>>>(qb, rbias, Wr, br, wb, cqb);
  k_attn<<<BT_,     256, 0, stream>>>(r, mask, qb, kb, vb, wb, cqb, attnb);
  k_proj<<<BT_ / 8, 256, 0, stream>>>(attnb, Wo, bo, x, x1b);
  k_ln  <<<BT_,     256, 0, stream>>>(x1b, g2, b2, h2b);
  k_ffn1<<<BT_ / 8, 256, 0, stream>>>(h2b, W1, fb1, midb);
  k_ffn2<<<BT_ / 8, 256, 0, stream>>>(midb, W2, fb2, x1b, out);
}

// Round 3
// 880.458 us; speedup vs baseline: 1.1976x; 1.1976x over previous
//
#include <hip/hip_runtime.h>
#include <math.h>

// Problem dims (fixed by setup_inputs)
constexpr int B_ = 2, T_ = 512, D_ = 256, H_ = 4, DK_ = 64;
constexpr int BT_ = B_ * T_;
constexpr int D4_ = 4 * D_;

#define F4E(v,i) ((i)==0?(v).x:((i)==1?(v).y:((i)==2?(v).z:(v).w)))

__device__ __forceinline__ float dot4(float4 a, float4 b) {
  return fmaf(a.x, b.x, fmaf(a.y, b.y, fmaf(a.z, b.z, a.w * b.w)));
}

// ============ K1: LN1 + QKV + (Wr-folded w, br-folded cq) ============
// 256 blocks x 256 threads, 4 rows/block
__global__ __launch_bounds__(256) void k1_ln_qkv_w(
    const float* __restrict__ x,
    const float* __restrict__ g1, const float* __restrict__ b1,
    const float* __restrict__ Wq, const float* __restrict__ bq,
    const float* __restrict__ Wk, const float* __restrict__ bk,
    const float* __restrict__ Wv, const float* __restrict__ bv,
    const float* __restrict__ rbias, const float* __restrict__ Wr,
    const float* __restrict__ br,
    float* __restrict__ q, float* __restrict__ k, float* __restrict__ v,
    float* __restrict__ w, float* __restrict__ cq) {
  __shared__ float hs[4][D_];
  __shared__ float us[4][D_];
  int t = threadIdx.x, lane = t & 63, wid = t >> 6;
  int row0 = blockIdx.x * 4, b = row0 >> 9;

  // LayerNorm: one wave per row
  {
    const float* xr = x + (size_t)(row0 + wid) * D_;
    float v0 = xr[lane], v1 = xr[lane + 64], v2 = xr[lane + 128], v3 = xr[lane + 192];
    float s = v0 + v1 + v2 + v3;
    float s2 = fmaf(v0, v0, fmaf(v1, v1, fmaf(v2, v2, v3 * v3)));
    #pragma unroll
    for (int o = 32; o > 0; o >>= 1) { s += __shfl_xor(s, o, 64); s2 += __shfl_xor(s2, o, 64); }
    float m = s * (1.0f / D_);
    float var = s2 * (1.0f / D_) - m * m;
    float rinv = rsqrtf(var + 1e-5f);
    hs[wid][lane]       = (v0 - m) * rinv * g1[lane]       + b1[lane];
    hs[wid][lane + 64]  = (v1 - m) * rinv * g1[lane + 64]  + b1[lane + 64];
    hs[wid][lane + 128] = (v2 - m) * rinv * g1[lane + 128] + b1[lane + 128];
    hs[wid][lane + 192] = (v3 - m) * rinv * g1[lane + 192] + b1[lane + 192];
  }
  __syncthreads();

  // QKV: thread t = output col, 4 rows
  float qa[4], ka[4], va[4];
  {
    float bqc = bq[t], bkc = bk[t], bvc = bv[t];
    #pragma unroll
    for (int r2 = 0; r2 < 4; r2++) { qa[r2] = bqc; ka[r2] = bkc; va[r2] = bvc; }
  }
  for (int d = 0; d < D_; d += 4) {
    float4 h4[4];
    #pragma unroll
    for (int r2 = 0; r2 < 4; r2++) h4[r2] = *(const float4*)&hs[r2][d];
    #pragma unroll
    for (int i = 0; i < 4; i++) {
      float wqv = Wq[(d + i) * D_ + t], wkv = Wk[(d + i) * D_ + t], wvv = Wv[(d + i) * D_ + t];
      #pragma unroll
      for (int r2 = 0; r2 < 4; r2++) {
        float hv = F4E(h4[r2], i);
        qa[r2] = fmaf(hv, wqv, qa[r2]);
        ka[r2] = fmaf(hv, wkv, ka[r2]);
        va[r2] = fmaf(hv, wvv, va[r2]);
      }
    }
  }
  int hh = t >> 6, dd = t & 63;
  float rb = rbias[t];
  #pragma unroll
  for (int r2 = 0; r2 < 4; r2++) {
    int tt = (row0 & 511) + r2;
    size_t idx = ((size_t)(b * H_ + hh) * T_ + tt) * DK_ + dd;
    q[idx] = qa[r2]; k[idx] = ka[r2]; v[idx] = va[r2];
    us[r2][t] = qa[r2] + rb;
  }
  __syncthreads();

  // w[bt][h][c=t] = sum_dd Wr[t, h*64+dd] * us[h*64+dd]
  float acc[4][4];
  #pragma unroll
  for (int r2 = 0; r2 < 4; r2++) {
    #pragma unroll
    for (int h2 = 0; h2 < 4; h2++) acc[r2][h2] = 0.0f;
  }
  const float4* wr4 = (const float4*)&Wr[(size_t)t * D_];
  #pragma unroll
  for (int h2 = 0; h2 < 4; h2++) {
    #pragma unroll 4
    for (int d4 = 0; d4 < 16; d4++) {
      float4 wv4 = wr4[h2 * 16 + d4];
      #pragma unroll
      for (int r2 = 0; r2 < 4; r2++) {
        float4 u4 = *(const float4*)&us[r2][h2 * 64 + d4 * 4];
        acc[r2][h2] = fmaf(wv4.x, u4.x, fmaf(wv4.y, u4.y,
                       fmaf(wv4.z, u4.z, fmaf(wv4.w, u4.w, acc[r2][h2]))));
      }
    }
  }
  #pragma unroll
  for (int r2 = 0; r2 < 4; r2++) {
    #pragma unroll
    for (int h2 = 0; h2 < 4; h2++)
      w[(size_t)((row0 + r2) * 4 + h2) * D_ + t] = acc[r2][h2];
  }
  if (t < 16) {
    int r2 = t >> 2, h2 = t & 3;
    float s = 0;
    for (int d2 = 0; d2 < 64; d2++) s = fmaf(us[r2][h2 * 64 + d2], br[h2 * 64 + d2], s);
    cq[(row0 + r2) * 4 + h2] = s;
  }
}

// ============ K2: scores + softmax + PV + O-proj + residual + LN2 ============
// 1024 blocks (one per (b,i)) x 256 threads
__global__ __launch_bounds__(256) void k2_attn(
    const float* __restrict__ r, const int* __restrict__ mask,
    const float* __restrict__ q, const float* __restrict__ k,
    const float* __restrict__ v, const float* __restrict__ w,
    const float* __restrict__ cq, const float* __restrict__ x,
    const float* __restrict__ Wo, const float* __restrict__ bo,
    const float* __restrict__ g2, const float* __restrict__ b2,
    float* __restrict__ x1, float* __restrict__ h2o) {
  __shared__ float sw[H_ * D_];   // 4 KB
  __shared__ float sq[D_];        // 1 KB
  __shared__ float sc[H_][T_];    // 8 KB
  __shared__ float ar[D_];        // 1 KB
  __shared__ float scq[H_];
  __shared__ float redA[4], redB[4];
  int t = threadIdx.x, lane = t & 63, wid = t >> 6, qt = lane & 15;
  int bi = blockIdx.x, b = bi >> 9, i = bi & (T_ - 1);

  #pragma unroll
  for (int u = 0; u < 4; u++) sw[u * 256 + t] = w[(size_t)bi * 1024 + u * 256 + t];
  sq[t] = q[((size_t)(b * H_ + wid) * T_ + i) * DK_ + lane];
  if (t < 4) scq[t] = cq[bi * 4 + t];
  __syncthreads();

  // per-lane fragments: lane qt owns c = 64u + 4qt + e  (u,e in 0..3)
  float4 wreg[4][4];  // [h][u]
  float4 qreg[4];     // [h]  dd = 4qt+e
  #pragma unroll
  for (int h = 0; h < 4; h++) {
    qreg[h] = *(const float4*)&sq[h * 64 + 4 * qt];
    #pragma unroll
    for (int u = 0; u < 4; u++)
      wreg[h][u] = *(const float4*)&sw[h * 256 + 64 * u + 4 * qt];
  }

  const float* rbase = r + (size_t)bi * (T_ * D_);
  const float* kbase = k + (size_t)b * (H_ * T_ * DK_);
  int rowoff = lane >> 4;  // 0..3: which of the 4 rows this lane's group handles
  float4 rA[4], kA[4];
  float4 rB[4] = {}, kB[4] = {};

  auto loadR = [&](int it, float4* rr) {
    int jr = wid * 128 + it * 4 + rowoff;
    const float4* rp = (const float4*)(rbase + (size_t)jr * D_);
    rr[0] = rp[qt]; rr[1] = rp[16 + qt]; rr[2] = rp[32 + qt]; rr[3] = rp[48 + qt];
  };
  auto loadK = [&](int it, float4* kk2) {
    int jr = wid * 128 + it * 4 + rowoff;
    #pragma unroll
    for (int h = 0; h < 4; h++)
      kk2[h] = *(const float4*)(kbase + ((size_t)h * T_ + jr) * DK_ + 4 * qt);
  };

  loadR(0, rA); loadK(0, kA);
  for (int it = 0; it < 32; ++it) {
    if (it < 31) { loadR(it + 1, rB); loadK(it + 1, kB); }
    float p0 = dot4(kA[0], qreg[0]) + dot4(rA[0], wreg[0][0]) + dot4(rA[1], wreg[0][1])
             + dot4(rA[2], wreg[0][2]) + dot4(rA[3], wreg[0][3]);
    float p1 = dot4(kA[1], qreg[1]) + dot4(rA[0], wreg[1][0]) + dot4(rA[1], wreg[1][1])
             + dot4(rA[2], wreg[1][2]) + dot4(rA[3], wreg[1][3]);
    float p2 = dot4(kA[2], qreg[2]) + dot4(rA[0], wreg[2][0]) + dot4(rA[1], wreg[2][1])
             + dot4(rA[2], wreg[2][2]) + dot4(rA[3], wreg[2][3]);
    float p3 = dot4(kA[3], qreg[3]) + dot4(rA[0], wreg[3][0]) + dot4(rA[1], wreg[3][1])
             + dot4(rA[2], wreg[3][2]) + dot4(rA[3], wreg[3][3]);
    // reduce over the 16-lane group (c and dd are spread across qt)
    #pragma unroll
    for (int off = 1; off <= 8; off <<= 1) {
      p0 += __shfl_xor(p0, off, 64);
      p1 += __shfl_xor(p1, off, 64);
      p2 += __shfl_xor(p2, off, 64);
      p3 += __shfl_xor(p3, off, 64);
    }
    if (qt < 4) {
      int jr = wid * 128 + it * 4 + rowoff;
      float val = (qt == 0) ? p0 : (qt == 1) ? p1 : (qt == 2) ? p2 : p3;
      float s = (val + scq[qt]) * 0.125f;
      if (mask[(size_t)bi * T_ + jr] == 0) s = -1e9f;
      sc[qt][jr] = s;
    }
    #pragma unroll
    for (int u = 0; u < 4; u++) { rA[u] = rB[u]; kA[u] = kB[u]; }
  }
  __syncthreads();

  // softmax (wave wid owns head wid) + PV, sum kept in registers via butterfly
  {
    float vals[8];
    float m = -3.0e38f;
    #pragma unroll
    for (int kk2 = 0; kk2 < 8; kk2++) { vals[kk2] = sc[wid][lane + 64 * kk2]; m = fmaxf(m, vals[kk2]); }
    #pragma unroll
    for (int o = 32; o > 0; o >>= 1) m = fmaxf(m, __shfl_xor(m, o, 64));
    float ss = 0;
    #pragma unroll
    for (int kk2 = 0; kk2 < 8; kk2++) {
      float e = expf(vals[kk2] - m);
      sc[wid][lane + 64 * kk2] = e;
      ss += e;
    }
    #pragma unroll
    for (int o = 32; o > 0; o >>= 1) ss += __shfl_xor(ss, o, 64);
    float inv = 1.0f / ss;

    const float* vp = v + (size_t)(b * H_ + wid) * T_ * DK_ + lane;
    float a2 = 0;
    #pragma unroll 4
    for (int j = 0; j < T_; j += 4) {
      float4 p4 = *(const float4*)&sc[wid][j];
      a2 = fmaf(p4.x, vp[(size_t)j * 64], a2);
      a2 = fmaf(p4.y, vp[(size_t)(j + 1) * 64], a2);
      a2 = fmaf(p4.z, vp[(size_t)(j + 2) * 64], a2);
      a2 = fmaf(p4.w, vp[(size_t)(j + 3) * 64], a2);
    }
    ar[t] = a2 * inv;   // output col t = wid*64 + lane
  }
  __syncthreads();

  // O-proj col t + residual + LN2
  float acc = bo[t];
  #pragma unroll 4
  for (int d4 = 0; d4 < 64; d4++) {
    float4 a4 = *(const float4*)&ar[4 * d4];
    acc = fmaf(a4.x, Wo[(4 * d4 + 0) * D_ + t], acc);
    acc = fmaf(a4.y, Wo[(4 * d4 + 1) * D_ + t], acc);
    acc = fmaf(a4.z, Wo[(4 * d4 + 2) * D_ + t], acc);
    acc = fmaf(a4.w, Wo[(4 * d4 + 3) * D_ + t], acc);
  }
  float x1v = x[(size_t)bi * D_ + t] + acc;
  float s1 = x1v, s2v = x1v * x1v;
  #pragma unroll
  for (int o = 32; o > 0; o >>= 1) { s1 += __shfl_xor(s1, o, 64); s2v += __shfl_xor(s2v, o, 64); }
  if (lane == 0) { redA[wid] = s1; redB[wid] = s2v; }
  __syncthreads();
  float mm = (redA[0] + redA[1] + redA[2] + redA[3]) * (1.0f / D_);
  float var = (redB[0] + redB[1] + redB[2] + redB[3]) * (1.0f / D_) - mm * mm;
  float rinv = rsqrtf(var + 1e-5f);
  x1[(size_t)bi * D_ + t] = x1v;
  h2o[(size_t)bi * D_ + t] = (x1v - mm) * rinv * g2[t] + b2[t];
}

// ============ K3: FFN1 + gelu(exact) + FFN2 + residual ============
// 256 blocks x 256 threads, 4 rows/block
__global__ __launch_bounds__(256) void k3_ffn(
    const float* __restrict__ h2, const float* __restrict__ W1,
    const float* __restrict__ fb1, const float* __restrict__ W2,
    const float* __restrict__ fb2, const float* __restrict__ x1,
    float* __restrict__ out) {
  __shared__ float hs[4][D_];
  __shared__ float ms[4][D4_];  // 16 KB
  int t = threadIdx.x, row0 = blockIdx.x * 4;
  #pragma unroll
  for (int r2 = 0; r2 < 4; r2++) hs[r2][t] = h2[(size_t)(row0 + r2) * D_ + t];
  __syncthreads();

  float acc[4][4];  // [row][col-chunk]
  #pragma unroll
  for (int c = 0; c < 4; c++) {
    float bb = fb1[t + 256 * c];
    #pragma unroll
    for (int r2 = 0; r2 < 4; r2++) acc[r2][c] = bb;
  }
  for (int d4 = 0; d4 < 64; d4++) {
    float4 h4[4];
    #pragma unroll
    for (int r2 = 0; r2 < 4; r2++) h4[r2] = *(const float4*)&hs[r2][4 * d4];
    #pragma unroll
    for (int i2 = 0; i2 < 4; i2++) {
      float wv0 = W1[(size_t)(4 * d4 + i2) * D4_ + t];
      float wv1 = W1[(size_t)(4 * d4 + i2) * D4_ + t + 256];
      float wv2 = W1[(size_t)(4 * d4 + i2) * D4_ + t + 512];
      float wv3 = W1[(size_t)(4 * d4 + i2) * D4_ + t + 768];
      #pragma unroll
      for (int r2 = 0; r2 < 4; r2++) {
        float hv = F4E(h4[r2], i2);
        acc[r2][0] = fmaf(hv, wv0, acc[r2][0]);
        acc[r2][1] = fmaf(hv, wv1, acc[r2][1]);
        acc[r2][2] = fmaf(hv, wv2, acc[r2][2]);
        acc[r2][3] = fmaf(hv, wv3, acc[r2][3]);
      }
    }
  }
  #pragma unroll
  for (int r2 = 0; r2 < 4; r2++) {
    #pragma unroll
    for (int c = 0; c < 4; c++) {
      float val = acc[r2][c];
      ms[r2][t + 256 * c] = 0.5f * val * (1.0f + erff(val * 0.70710678118654752f));
    }
  }
  __syncthreads();

  float a2[4];
  float bb2 = fb2[t];
  #pragma unroll
  for (int r2 = 0; r2 < 4; r2++) a2[r2] = bb2;
  for (int d4 = 0; d4 < 256; d4++) {
    float4 m4[4];
    #pragma unroll
    for (int r2 = 0; r2 < 4; r2++) m4[r2] = *(const float4*)&ms[r2][4 * d4];
    #pragma unroll
    for (int i2 = 0; i2 < 4; i2++) {
      float wv = W2[(size_t)(4 * d4 + i2) * D_ + t];
      #pragma unroll
      for (int r2 = 0; r2 < 4; r2++) a2[r2] = fmaf(F4E(m4[r2], i2), wv, a2[r2]);
    }
  }
  #pragma unroll
  for (int r2 = 0; r2 < 4; r2++)
    out[(size_t)(row0 + r2) * D_ + t] = x1[(size_t)(row0 + r2) * D_ + t] + a2[r2];
}

extern "C" void kernel_launch(void* const* d_in, const int* in_sizes, int n_in,
                              void* d_out, int out_size, void* d_ws, size_t ws_size,
                              hipStream_t stream) {
  const float* x     = (const float*)d_in[0];
  const float* r     = (const float*)d_in[1];
  const int*   mask  = (const int*)d_in[2];
  const float* Wq = (const float*)d_in[5];  const float* bq = (const float*)d_in[6];
  const float* Wk = (const float*)d_in[7];  const float* bk = (const float*)d_in[8];
  const float* Wv = (const float*)d_in[9];  const float* bv = (const float*)d_in[10];
  const float* Wr = (const float*)d_in[11]; const float* br = (const float*)d_in[12];
  const float* rbias = (const float*)d_in[13];
  const float* Wo = (const float*)d_in[14]; const float* bo = (const float*)d_in[15];
  const float* g1 = (const float*)d_in[16]; const float* b1 = (const float*)d_in[17];
  const float* g2 = (const float*)d_in[18]; const float* b2 = (const float*)d_in[19];
  const float* W1 = (const float*)d_in[20]; const float* fb1 = (const float*)d_in[21];
  const float* W2 = (const float*)d_in[22]; const float* fb2 = (const float*)d_in[23];
  float* out = (float*)d_out;

  float* ws = (float*)d_ws;
  float* qb  = ws;                 // 262144
  float* kb  = ws + 262144;        // 262144
  float* vb  = ws + 524288;        // 262144
  float* wb  = ws + 786432;        // 1048576
  float* cqb = ws + 1835008;       // 4096
  float* x1b = ws + 1839104;       // 262144
  float* h2b = ws + 2101248;       // 262144

  k1_ln_qkv_w<<<BT_ / 4, 256, 0, stream>>>(x, g1, b1, Wq, bq, Wk, bk, Wv, bv,
                                           rbias, Wr, br, qb, kb, vb, wb, cqb);
  k2_attn<<<BT_, 256, 0, stream>>>(r, mask, qb, kb, vb, wb, cqb, x,
                                   Wo, bo, g2, b2, x1b, h2b);
  k3_ffn<<<BT_ / 4, 256, 0, stream>>>(h2b, W1, fb1, W2, fb2, x1b, out);
}